// Round 1
// baseline (116.757 us; speedup 1.0000x reference)
//
#include <hip/hip_runtime.h>
#include <math.h>

// ---------------------------------------------------------------------------
// HybridQuantumDQN: encoder MLP -> 8-qubit statevector sim -> decoder MLP.
// R11: (1) final RY layer removed — observables rotated instead:
//      RY^dag Z RY = cosT*Z - sinT*X, so out_w = cosT_w*<Z_w> - sinT_w*<X_w>
//      with <X_w> from 8 packed-fma correlator reductions on the pre-rotation
//      state (saves ~290 VALU inst/lane vs ry_cross/ry_inlane).
//      (2) scalar-coefficient VOP3P ops: coefficient broadcast via
//      op_sel_hi[0]=0 (both halves read word0) instead of (v2f){c,c} v_movs.
// Base (R7): 8 samples/wave64; 8 lanes/sample; 32 complex amps/lane (v2f);
// sample's 8 lanes on lane bits {0,1,3} so cross-wire exchanges are all DPP
// (xor1/xor2 = quad_perm, xor8 = row_ror:8). amp = (G<<5)|t: G = lane bits
// {3,1,0} (amp bits 7..5), t = reg idx (amp bits 4..0). Wires 0..2 cross,
// 3..7 in-lane. Layer 0 = product state. CZ = closed-form +-1 diagonal.
//
// Session conclusions (measured): VALU-issue/latency bound (VALUBusy ~49%,
// HBM 0.27%, 0 LDS conflicts). Residency changes, LDS transposes, ds_swizzle
// vs DPP, and MFMA reformulation all measured neutral-to-worse (R4-R10).
// launch_bounds min-waves >4 forces scratch spill. Keep (128, 2).
// ---------------------------------------------------------------------------

#define PI_F 3.14159265358979323846f

typedef float v2f __attribute__((ext_vector_type(2)));

struct C2 { float re, im; };
__device__ __forceinline__ C2 cmul(C2 a, C2 b) {
    C2 r;
    r.re = fmaf(a.re, b.re, -a.im * b.im);
    r.im = fmaf(a.re, b.im,  a.im * b.re);
    return r;
}
__device__ __forceinline__ float fxor(float x, int m) {
    return __int_as_float(__float_as_int(x) ^ m);
}

// ---------------- packed fp32 primitives (VOP3P) ----------------
// componentwise v2f fma — used by the X-correlators
__device__ __forceinline__ v2f pk_fma(v2f a, v2f b, v2f c) {
    v2f d; asm("v_pk_fma_f32 %0, %1, %2, %3" : "=v"(d) : "v"(a), "v"(b), "v"(c)); return d;
}

// scalar-coefficient variants: coefficient lives in word0 of its VGPR pair;
// op_sel_hi[0]=0 makes BOTH result halves read word0 (free HW broadcast).
// word1 of the pair is never read, so it is left undefined (no v_mov).
__device__ __forceinline__ v2f mkbc(float c) { v2f r; r.x = c; return r; }

__device__ __forceinline__ v2f pk_mul_s(float c, v2f z) {
    v2f cb = mkbc(c), d;
    asm("v_pk_mul_f32 %0, %1, %2 op_sel_hi:[0,1]"
        : "=v"(d) : "v"(cb), "v"(z));
    return d;
}
__device__ __forceinline__ v2f pk_mul_neg_s(float c, v2f z) {
    v2f cb = mkbc(c), d;
    asm("v_pk_mul_f32 %0, %1, %2 op_sel_hi:[0,1] neg_lo:[1,0] neg_hi:[1,0]"
        : "=v"(d) : "v"(cb), "v"(z));
    return d;
}
__device__ __forceinline__ v2f pk_fma_s(float c, v2f b, v2f acc) {
    v2f cb = mkbc(c), d;
    asm("v_pk_fma_f32 %0, %1, %2, %3 op_sel_hi:[0,1,1]"
        : "=v"(d) : "v"(cb), "v"(b), "v"(acc));
    return d;
}
// d = -(c*b) + acc
__device__ __forceinline__ v2f pk_fma_nn_s(float c, v2f b, v2f acc) {
    v2f cb = mkbc(c), d;
    asm("v_pk_fma_f32 %0, %1, %2, %3 op_sel_hi:[0,1,1] neg_lo:[1,0,0] neg_hi:[1,0,0]"
        : "=v"(d) : "v"(cb), "v"(b), "v"(acc));
    return d;
}
// d.lo = -c*z.hi + acc.lo ; d.hi = c*z.lo + acc.hi   (complex cross term)
__device__ __forceinline__ v2f pk_fma_swl_s(float c, v2f z, v2f acc) {
    v2f cb = mkbc(c), d;
    asm("v_pk_fma_f32 %0, %1, %2, %3 op_sel:[0,1,0] op_sel_hi:[0,0,1] neg_lo:[1,0,0]"
        : "=v"(d) : "v"(cb), "v"(z), "v"(acc));
    return d;
}
// d.lo = c*z.hi + acc.lo ; d.hi = -c*z.lo + acc.hi
__device__ __forceinline__ v2f pk_fma_swh_s(float c, v2f z, v2f acc) {
    v2f cb = mkbc(c), d;
    asm("v_pk_fma_f32 %0, %1, %2, %3 op_sel:[0,1,0] op_sel_hi:[0,0,1] neg_hi:[1,0,0]"
        : "=v"(d) : "v"(cb), "v"(z), "v"(acc));
    return d;
}
// z * (re + i*im), complex scalar coefficient
__device__ __forceinline__ v2f cmulv(v2f z, C2 c) {
    return pk_fma_swl_s(c.im, z, pk_mul_s(c.re, z));
}

// ---------------- cross-lane exchange (all DPP) ----------------
template<int CTRL>
__device__ __forceinline__ float dppf(float x) {
    int xi = __float_as_int(x);
    int r = __builtin_amdgcn_update_dpp(xi, xi, CTRL, 0xF, 0xF, false);
    return __int_as_float(r);
}
template<int M>
__device__ __forceinline__ float lxor(float x) {
    if constexpr (M == 1)      return dppf<0xB1>(x);   // quad_perm [1,0,3,2]
    else if constexpr (M == 2) return dppf<0x4E>(x);   // quad_perm [2,3,0,1]
    else                       return dppf<0x128>(x);  // row_ror:8 == lane^8 in row16
}

// ---------------- gates ----------------
// fused SU(2) gate G = Rot * RY: columns (a,b); G = [[a,-conj(b)],[b,conj(a)]]
__device__ __forceinline__ void load_G2(const float* __restrict__ c_lds, int g,
                                        float cc, float ss,
                                        float& ar, float& ai, float& br, float& bi) {
    const float4 c0 = *(const float4*)(c_lds + 4 * g);  // aR.re aR.im bR.re bR.im
    ar = fmaf(c0.x, cc, -c0.z * ss);
    ai = fmaf(c0.y, cc,  c0.w * ss);
    br = fmaf(c0.z, cc,  c0.x * ss);
    bi = fmaf(c0.w, cc, -c0.y * ss);
}

// cross-lane SU(2): new = cS*z + cO*p, coefficients pre-sign-adjusted per lane
// (lo lane: cS=(ar,ai), cO=(-br,bi); hi lane: cS=(ar,-ai), cO=(br,bi))
// Chunked: gather 8 regs' partners via DPP, then the 32 pk ops.
template<int M>
__device__ __forceinline__ void su2_cross(float cSr, float cSi, float cOr, float cOi,
                                          v2f z[32]) {
#pragma unroll
    for (int c = 0; c < 4; c++) {
        v2f p[8];
#pragma unroll
        for (int k = 0; k < 8; k++) {
            p[k].x = lxor<M>(z[c * 8 + k].x);
            p[k].y = lxor<M>(z[c * 8 + k].y);
        }
#pragma unroll
        for (int k = 0; k < 8; k++) {
            const int t = c * 8 + k;
            v2f n = pk_mul_s(cSr, z[t]);
            n = pk_fma_swl_s(cSi, z[t], n);
            n = pk_fma_s    (cOr, p[k], n);
            n = pk_fma_swl_s(cOi, p[k], n);
            z[t] = n;
        }
    }
}

// in-lane SU(2) on reg-index bit ST
template<int ST>
__device__ __forceinline__ void su2_inlane(float ar, float ai, float br, float bi,
                                           v2f z[32]) {
#pragma unroll
    for (int t = 0; t < 32; t++) {
        if ((t & ST) == 0) {
            const int u = t + ST;
            v2f x = z[t], y = z[u];
            v2f nx = pk_mul_s(ar, x);       // a*x
            nx = pk_fma_swl_s(ai, x, nx);
            nx = pk_fma_nn_s (br, y, nx);   // - conj(b)*y
            nx = pk_fma_swl_s(bi, y, nx);
            v2f ny = pk_mul_s(br, x);       // b*x
            ny = pk_fma_swl_s(bi, x, ny);
            ny = pk_fma_s    (ar, y, ny);   // + conj(a)*y
            ny = pk_fma_swh_s(ai, y, ny);
            z[t] = nx; z[u] = ny;
        }
    }
}

// ---------------- X correlators: <X_w> = sum_k Re(conj(z_k) z_{k^w}) --------
// cross wire (partner in lane^M): per-lane partial sum over the 32 own amps
template<int M>
__device__ __forceinline__ v2f xcorr_cross(const v2f z[32]) {
    v2f acc = (v2f){0.0f, 0.0f};
#pragma unroll
    for (int c = 0; c < 4; c++) {
        v2f p[8];
#pragma unroll
        for (int k = 0; k < 8; k++) {
            p[k].x = lxor<M>(z[c * 8 + k].x);
            p[k].y = lxor<M>(z[c * 8 + k].y);
        }
#pragma unroll
        for (int k = 0; k < 8; k++) acc = pk_fma(z[c * 8 + k], p[k], acc);
    }
    return acc;
}
// in-lane wire (reg bit ST): per-lane sum over the 16 pairs (each once)
template<int ST>
__device__ __forceinline__ v2f xcorr_inlane(const v2f z[32]) {
    v2f acc = (v2f){0.0f, 0.0f};
#pragma unroll
    for (int t = 0; t < 32; t++)
        if ((t & ST) == 0) acc = pk_fma(z[t], z[t + ST], acc);
    return acc;
}

// CZ t-part (5-bit): parity of adjacent-bit ANDs
__host__ __device__ constexpr bool czt5(int t) {
    return ((((t >> 4) & (t >> 3)) ^ ((t >> 3) & (t >> 2)) ^
             ((t >> 2) & (t >> 1)) ^ ((t >> 1) & t)) & 1) != 0;
}

__global__ __launch_bounds__(128, 2) void qdqn_kernel(
    const float* __restrict__ x,
    const float* __restrict__ ew1, const float* __restrict__ eb1,
    const float* __restrict__ ew2, const float* __restrict__ eb2,
    const float* __restrict__ qw,
    const float* __restrict__ dw1, const float* __restrict__ db1,
    const float* __restrict__ dw2, const float* __restrict__ db2,
    float* __restrict__ out, int B, int NL) {
    __shared__ __align__(16) float c_lds[32 * 4];
    __shared__ __align__(16) float hx[2][8][8];     // h / h2 exchange
    __shared__ __align__(16) float csx[2][8][16];   // (c,s) exchange

    const int tid = threadIdx.x;
    const int wave = tid >> 6;
    const int lane = tid & 63;
    // sample lane bits {0,1,3}; sample id bits {2,4,5} -> all-DPP cross wires
    const int g = (lane & 3) | ((lane >> 1) & 4);          // amp bits 7..5
    const int grp = ((lane >> 2) & 1) | ((lane >> 3) & 6); // sample in wave
    int s = blockIdx.x * 16 + wave * 8 + grp;
    if (s >= B) s = B - 1;

    // ---- prefetch x early (overlaps coef computation + barrier) ----
    float xv[16];
    {
        const float4* xp = (const float4*)(x + s * 16);
#pragma unroll
        for (int i = 0; i < 4; i++) {
            float4 v = xp[i];
            xv[4*i] = v.x; xv[4*i+1] = v.y; xv[4*i+2] = v.z; xv[4*i+3] = v.w;
        }
    }

    // ---- Rot SU(2) coeffs once per block: a = e^{-iA}c, b = e^{-iB}s ----
    const int n_gates = NL * 8;
    if (tid < n_gates) {
        const int gg = tid;
        float phi = qw[3 * gg + 0], th = qw[3 * gg + 1], om = qw[3 * gg + 2];
        float c = __cosf(0.5f * th), sv = __sinf(0.5f * th);
        float A = 0.5f * (phi + om), Bb = 0.5f * (phi - om);
        float* o = c_lds + 4 * gg;
        o[0] =  __cosf(A) * c;   o[1] = -__sinf(A) * c;
        o[2] =  __cosf(Bb) * sv; o[3] = -__sinf(Bb) * sv;
    }
    __syncthreads();

    // ---------------- encoder MLP, split across the 8 lanes ----------------
    float cq[8], sq[8];
    {
        // lane computes row g of W1
        float a = eb1[g];
#pragma unroll
        for (int i = 0; i < 16; i++) a = fmaf(ew1[g * 16 + i], xv[i], a);
        hx[wave][grp][g] = fmaxf(a, 0.0f);
        __builtin_amdgcn_wave_barrier();
        float4 h01 = *(const float4*)&hx[wave][grp][0];
        float4 h23 = *(const float4*)&hx[wave][grp][4];
        // lane computes qubit g of layer 2 + transcendentals
        float b = eb2[g];
        b = fmaf(ew2[g*8+0], h01.x, b); b = fmaf(ew2[g*8+1], h01.y, b);
        b = fmaf(ew2[g*8+2], h01.z, b); b = fmaf(ew2[g*8+3], h01.w, b);
        b = fmaf(ew2[g*8+4], h23.x, b); b = fmaf(ew2[g*8+5], h23.y, b);
        b = fmaf(ew2[g*8+6], h23.z, b); b = fmaf(ew2[g*8+7], h23.w, b);
        float e = 1.0f - __fdividef(2.0f, __expf(2.0f * b) + 1.0f);  // tanh
        float ang = e * (0.5f * PI_F);
        float2* cso = (float2*)&csx[wave][grp][2 * g];
        *cso = make_float2(__cosf(ang), __sinf(ang));
        __builtin_amdgcn_wave_barrier();
#pragma unroll
        for (int k = 0; k < 4; k++) {
            float4 v = *(const float4*)&csx[wave][grp][4 * k];
            cq[2*k] = v.x; sq[2*k] = v.y; cq[2*k+1] = v.z; sq[2*k+1] = v.w;
        }
    }

    // ---- per-lane sign masks for cross wires q=0..2 (logical bit 2-q of g)
    int hiM[3], loM[3];
#pragma unroll
    for (int q = 0; q < 3; q++) {
        int hi = (g >> (2 - q)) & 1;
        hiM[q] = hi << 31;                 // flips ai when hi lane
        loM[q] = hiM[q] ^ 0x80000000;      // flips br when lo lane
    }

    // ---- CZ lane scalars: amp=(G<<5)|t; pairs (G2&G1)+(G1&G0)+(G0&t4)+t-part
    const int g0b = g & 1, g1b = (g >> 1) & 1, g2b = (g >> 2) & 1;
    const float mLo = ((g2b & g1b) ^ (g1b & g0b)) ? -1.0f : 1.0f;  // t < 16
    const float mHi = g0b ? -mLo : mLo;                            // t >= 16

    // ---------------- layer 0: product state, CZ folded --------------------
    v2f z[32];
    {
        C2 P; P.re = 1.0f; P.im = 0.0f;
        C2 A[5], Bc[5];
#pragma unroll
        for (int q = 0; q < 8; q++) {
            float ar, ai, br, bi;
            load_G2(c_lds, q, cq[q], sq[q], ar, ai, br, bi);
            if (q < 3) {
                const bool hi = (g >> (2 - q)) & 1;
                C2 f; f.re = hi ? br : ar; f.im = hi ? bi : ai;  // column 0
                P = cmul(P, f);
            } else {
                A[q-3].re = ar;  A[q-3].im = ai;
                Bc[q-3].re = br; Bc[q-3].im = bi;
            }
        }
        z[0] = (v2f){P.re, P.im};
#pragma unroll
        for (int w = 0; w < 5; w++) {
            const int n = 1 << w;
#pragma unroll
            for (int i = n - 1; i >= 0; i--) {
                v2f v = z[i];
                z[2*i+1] = cmulv(v, Bc[w]);
                z[2*i]   = cmulv(v, A[w]);
            }
        }
#pragma unroll
        for (int t = 0; t < 32; t++) {
            const float m = (t < 16) ? mLo : mHi;
            z[t] = czt5(t) ? pk_mul_neg_s(m, z[t]) : pk_mul_s(m, z[t]);
        }
    }

    // ---------------- layers 1..NL-1 ---------------------------------------
    for (int l = 1; l < NL; l++) {
        const int gb = l * 8;
        float ar, ai, br, bi;
        load_G2(c_lds, gb+0, cq[0], sq[0], ar, ai, br, bi);
        su2_cross<8>(ar, fxor(ai,hiM[0]), fxor(br,loM[0]), bi, z);
        load_G2(c_lds, gb+1, cq[1], sq[1], ar, ai, br, bi);
        su2_cross<2>(ar, fxor(ai,hiM[1]), fxor(br,loM[1]), bi, z);
        load_G2(c_lds, gb+2, cq[2], sq[2], ar, ai, br, bi);
        su2_cross<1>(ar, fxor(ai,hiM[2]), fxor(br,loM[2]), bi, z);
        load_G2(c_lds, gb+3, cq[3], sq[3], ar, ai, br, bi);
        su2_inlane<16>(ar, ai, br, bi, z);
        load_G2(c_lds, gb+4, cq[4], sq[4], ar, ai, br, bi);
        su2_inlane<8>(ar, ai, br, bi, z);
        load_G2(c_lds, gb+5, cq[5], sq[5], ar, ai, br, bi);
        su2_inlane<4>(ar, ai, br, bi, z);
        load_G2(c_lds, gb+6, cq[6], sq[6], ar, ai, br, bi);
        su2_inlane<2>(ar, ai, br, bi, z);
        load_G2(c_lds, gb+7, cq[7], sq[7], ar, ai, br, bi);
        su2_inlane<1>(ar, ai, br, bi, z);
        // CZ diagonal
#pragma unroll
        for (int t = 0; t < 32; t++) {
            const float m = (t < 16) ? mLo : mHi;
            z[t] = czt5(t) ? pk_mul_neg_s(m, z[t]) : pk_mul_s(m, z[t]);
        }
    }

    // ---------------- readout: rotated observables --------------------------
    // The final RY(T_w) layer is NOT applied to the state. Instead:
    //   <Z_w>_final = cosT_w * <Z_w> - sinT_w * <X_w>   (RY^dag Z RY identity;
    // RY's on other wires commute through Z_w). cq/sq hold half-angle cos/sin:
    // cosT = cq^2 - sq^2, sinT = 2*cq*sq. In-lane correlators count each pair
    // once per lane (-> coeff 2*sinT); cross correlators count each ordered
    // pair once across the two lanes (-> coeff sinT after the all-reduce).
    v2f xa[8];
    xa[0] = xcorr_cross<8>(z);
    xa[1] = xcorr_cross<2>(z);
    xa[2] = xcorr_cross<1>(z);
    xa[3] = xcorr_inlane<16>(z);
    xa[4] = xcorr_inlane<8>(z);
    xa[5] = xcorr_inlane<4>(z);
    xa[6] = xcorr_inlane<2>(z);
    xa[7] = xcorr_inlane<1>(z);

    float p[32];
#pragma unroll
    for (int t = 0; t < 32; t++) p[t] = fmaf(z[t].x, z[t].x, z[t].y * z[t].y);

    float s16[16], zW[8];
    {
        float d = 0.0f;
#pragma unroll
        for (int i = 0; i < 16; i++) {
            s16[i] = p[2*i] + p[2*i+1];
            d += p[2*i] - p[2*i+1];
        }
        zW[7] = d;
        float s8[8]; d = 0.0f;
#pragma unroll
        for (int i = 0; i < 8; i++) {
            s8[i] = s16[2*i] + s16[2*i+1];
            d += s16[2*i] - s16[2*i+1];
        }
        zW[6] = d;
        float s4[4]; d = 0.0f;
#pragma unroll
        for (int i = 0; i < 4; i++) {
            s4[i] = s8[2*i] + s8[2*i+1];
            d += s8[2*i] - s8[2*i+1];
        }
        zW[5] = d;
        float s2a = s4[0] + s4[1], s2b = s4[2] + s4[3];
        zW[4] = (s4[0] - s4[1]) + (s4[2] - s4[3]);
        float sumP = s2a + s2b;
        zW[3] = s2a - s2b;
        zW[0] = g2b ? -sumP : sumP;
        zW[1] = g1b ? -sumP : sumP;
        zW[2] = g0b ? -sumP : sumP;
    }

    // rotate observables (per-lane partials; linear in the later all-reduce)
#pragma unroll
    for (int w = 0; w < 8; w++) {
        const float c2 = fmaf(cq[w], cq[w], -sq[w] * sq[w]);   // cos T
        const float cs = cq[w] * sq[w];
        const float s2 = (w < 3 ? 2.0f : 4.0f) * cs;           // sinT (x2 in-lane)
        zW[w] = fmaf(c2, zW[w], -s2 * (xa[w].x + xa[w].y));
    }

    // all-reduce across the 8 lanes of the sample (bits 0,1,3 -> all DPP)
#pragma unroll
    for (int w = 0; w < 8; w++) zW[w] += lxor<1>(zW[w]);
#pragma unroll
    for (int w = 0; w < 8; w++) zW[w] += lxor<2>(zW[w]);
#pragma unroll
    for (int w = 0; w < 8; w++) zW[w] += lxor<8>(zW[w]);

    // ---------------- decoder MLP, split across lanes ----------------------
    {
        float a = db1[g];
#pragma unroll
        for (int w = 0; w < 8; w++) a = fmaf(dw1[g * 8 + w], zW[w], a);
        hx[wave][grp][g] = fmaxf(a, 0.0f);
        __builtin_amdgcn_wave_barrier();
        float4 h01 = *(const float4*)&hx[wave][grp][0];
        float4 h23 = *(const float4*)&hx[wave][grp][4];
        const int o = g & 3;   // lanes g and g+4 compute identical output o
        float acc = db2[o];
        acc = fmaf(dw2[o*8+0], h01.x, acc); acc = fmaf(dw2[o*8+1], h01.y, acc);
        acc = fmaf(dw2[o*8+2], h01.z, acc); acc = fmaf(dw2[o*8+3], h01.w, acc);
        acc = fmaf(dw2[o*8+4], h23.x, acc); acc = fmaf(dw2[o*8+5], h23.y, acc);
        acc = fmaf(dw2[o*8+6], h23.z, acc); acc = fmaf(dw2[o*8+7], h23.w, acc);
        out[s * 4 + o] = acc;
    }
}

extern "C" void kernel_launch(void* const* d_in, const int* in_sizes, int n_in,
                              void* d_out, int out_size, void* d_ws, size_t ws_size,
                              hipStream_t stream) {
    const float* x   = (const float*)d_in[0];
    const float* ew1 = (const float*)d_in[1];
    const float* eb1 = (const float*)d_in[2];
    const float* ew2 = (const float*)d_in[3];
    const float* eb2 = (const float*)d_in[4];
    const float* qw  = (const float*)d_in[5];
    const float* dw1 = (const float*)d_in[6];
    const float* db1 = (const float*)d_in[7];
    const float* dw2 = (const float*)d_in[8];
    const float* db2 = (const float*)d_in[9];
    float* out = (float*)d_out;

    int B = in_sizes[0] / 16;        // 32768
    int n_gates = in_sizes[5] / 3;   // 32
    int NL = n_gates / 8;            // 4

    // 16 samples per 128-thread block (2 waves x 8 samples/wave)
    int blocks = (B + 15) / 16;
    qdqn_kernel<<<blocks, 128, 0, stream>>>(x, ew1, eb1, ew2, eb2, qw,
                                            dw1, db1, dw2, db2, out, B, NL);
}

// Round 2
// 116.036 us; speedup vs baseline: 1.0062x; 1.0062x over previous
//
#include <hip/hip_runtime.h>
#include <math.h>

// ---------------------------------------------------------------------------
// HybridQuantumDQN: encoder MLP -> 8-qubit statevector sim -> decoder MLP.
// R12: 1-wave (64-thread) blocks, 4096 blocks. No __syncthreads — all LDS
//      exchange is wave-internal (in-order LDS + wave_barrier ordering).
//      Per-layer gate-coeff float4s hoisted to registers at loop top.
//      Goal: raise effective residency (Occupancy was 22% with 2-wave
//      blocks despite grid supplying 4 waves/SIMD) and remove cross-wave
//      sync skew. R11 (observable rotation + op_sel_hi broadcast) kept.
// R11: final RY layer removed — observables rotated instead:
//      RY^dag Z RY = cosT*Z - sinT*X; <X_w> via packed-fma correlators.
//      Scalar-coefficient VOP3P ops broadcast via op_sel_hi[0]=0.
// Base (R7): 8 samples/wave64; 8 lanes/sample; 32 complex amps/lane (v2f);
// sample's 8 lanes on lane bits {0,1,3} so cross-wire exchanges are all DPP
// (xor1/xor2 = quad_perm, xor8 = row_ror:8). amp = (G<<5)|t: G = lane bits
// {3,1,0} (amp bits 7..5), t = reg idx (amp bits 4..0). Wires 0..2 cross,
// 3..7 in-lane. Layer 0 = product state. CZ = closed-form +-1 diagonal.
//
// Session conclusions (measured): VALU-stall bound, not issue-count bound
// (R11: -8% insts -> harness unchanged; R9: +8% insts -> slightly worse).
// HBM 0.4%, 0 LDS conflicts. MFMA reformulation slower (R10). launch_bounds
// min-waves >4 forces scratch spill (R8).
// ---------------------------------------------------------------------------

#define PI_F 3.14159265358979323846f

typedef float v2f __attribute__((ext_vector_type(2)));

struct C2 { float re, im; };
__device__ __forceinline__ C2 cmul(C2 a, C2 b) {
    C2 r;
    r.re = fmaf(a.re, b.re, -a.im * b.im);
    r.im = fmaf(a.re, b.im,  a.im * b.re);
    return r;
}
__device__ __forceinline__ float fxor(float x, int m) {
    return __int_as_float(__float_as_int(x) ^ m);
}

// ---------------- packed fp32 primitives (VOP3P) ----------------
// componentwise v2f fma — used by the X-correlators
__device__ __forceinline__ v2f pk_fma(v2f a, v2f b, v2f c) {
    v2f d; asm("v_pk_fma_f32 %0, %1, %2, %3" : "=v"(d) : "v"(a), "v"(b), "v"(c)); return d;
}

// scalar-coefficient variants: coefficient lives in word0 of its VGPR pair;
// op_sel_hi[0]=0 makes BOTH result halves read word0 (free HW broadcast).
// word1 of the pair is never read, so it is left undefined (no v_mov).
__device__ __forceinline__ v2f mkbc(float c) { v2f r; r.x = c; return r; }

__device__ __forceinline__ v2f pk_mul_s(float c, v2f z) {
    v2f cb = mkbc(c), d;
    asm("v_pk_mul_f32 %0, %1, %2 op_sel_hi:[0,1]"
        : "=v"(d) : "v"(cb), "v"(z));
    return d;
}
__device__ __forceinline__ v2f pk_mul_neg_s(float c, v2f z) {
    v2f cb = mkbc(c), d;
    asm("v_pk_mul_f32 %0, %1, %2 op_sel_hi:[0,1] neg_lo:[1,0] neg_hi:[1,0]"
        : "=v"(d) : "v"(cb), "v"(z));
    return d;
}
__device__ __forceinline__ v2f pk_fma_s(float c, v2f b, v2f acc) {
    v2f cb = mkbc(c), d;
    asm("v_pk_fma_f32 %0, %1, %2, %3 op_sel_hi:[0,1,1]"
        : "=v"(d) : "v"(cb), "v"(b), "v"(acc));
    return d;
}
// d = -(c*b) + acc
__device__ __forceinline__ v2f pk_fma_nn_s(float c, v2f b, v2f acc) {
    v2f cb = mkbc(c), d;
    asm("v_pk_fma_f32 %0, %1, %2, %3 op_sel_hi:[0,1,1] neg_lo:[1,0,0] neg_hi:[1,0,0]"
        : "=v"(d) : "v"(cb), "v"(b), "v"(acc));
    return d;
}
// d.lo = -c*z.hi + acc.lo ; d.hi = c*z.lo + acc.hi   (complex cross term)
__device__ __forceinline__ v2f pk_fma_swl_s(float c, v2f z, v2f acc) {
    v2f cb = mkbc(c), d;
    asm("v_pk_fma_f32 %0, %1, %2, %3 op_sel:[0,1,0] op_sel_hi:[0,0,1] neg_lo:[1,0,0]"
        : "=v"(d) : "v"(cb), "v"(z), "v"(acc));
    return d;
}
// d.lo = c*z.hi + acc.lo ; d.hi = -c*z.lo + acc.hi
__device__ __forceinline__ v2f pk_fma_swh_s(float c, v2f z, v2f acc) {
    v2f cb = mkbc(c), d;
    asm("v_pk_fma_f32 %0, %1, %2, %3 op_sel:[0,1,0] op_sel_hi:[0,0,1] neg_hi:[1,0,0]"
        : "=v"(d) : "v"(cb), "v"(z), "v"(acc));
    return d;
}
// z * (re + i*im), complex scalar coefficient
__device__ __forceinline__ v2f cmulv(v2f z, C2 c) {
    return pk_fma_swl_s(c.im, z, pk_mul_s(c.re, z));
}

// ---------------- cross-lane exchange (all DPP) ----------------
template<int CTRL>
__device__ __forceinline__ float dppf(float x) {
    int xi = __float_as_int(x);
    int r = __builtin_amdgcn_update_dpp(xi, xi, CTRL, 0xF, 0xF, false);
    return __int_as_float(r);
}
template<int M>
__device__ __forceinline__ float lxor(float x) {
    if constexpr (M == 1)      return dppf<0xB1>(x);   // quad_perm [1,0,3,2]
    else if constexpr (M == 2) return dppf<0x4E>(x);   // quad_perm [2,3,0,1]
    else                       return dppf<0x128>(x);  // row_ror:8 == lane^8 in row16
}

// ---------------- gates ----------------
// fused SU(2) gate G = Rot * RY from a preloaded coeff float4:
// columns (a,b); G = [[a,-conj(b)],[b,conj(a)]]
__device__ __forceinline__ void make_G2(float4 c0, float cc, float ss,
                                        float& ar, float& ai, float& br, float& bi) {
    ar = fmaf(c0.x, cc, -c0.z * ss);
    ai = fmaf(c0.y, cc,  c0.w * ss);
    br = fmaf(c0.z, cc,  c0.x * ss);
    bi = fmaf(c0.w, cc, -c0.y * ss);
}

// cross-lane SU(2): new = cS*z + cO*p, coefficients pre-sign-adjusted per lane
// (lo lane: cS=(ar,ai), cO=(-br,bi); hi lane: cS=(ar,-ai), cO=(br,bi))
// Chunked: gather 8 regs' partners via DPP, then the 32 pk ops.
template<int M>
__device__ __forceinline__ void su2_cross(float cSr, float cSi, float cOr, float cOi,
                                          v2f z[32]) {
#pragma unroll
    for (int c = 0; c < 4; c++) {
        v2f p[8];
#pragma unroll
        for (int k = 0; k < 8; k++) {
            p[k].x = lxor<M>(z[c * 8 + k].x);
            p[k].y = lxor<M>(z[c * 8 + k].y);
        }
#pragma unroll
        for (int k = 0; k < 8; k++) {
            const int t = c * 8 + k;
            v2f n = pk_mul_s(cSr, z[t]);
            n = pk_fma_swl_s(cSi, z[t], n);
            n = pk_fma_s    (cOr, p[k], n);
            n = pk_fma_swl_s(cOi, p[k], n);
            z[t] = n;
        }
    }
}

// in-lane SU(2) on reg-index bit ST
template<int ST>
__device__ __forceinline__ void su2_inlane(float ar, float ai, float br, float bi,
                                           v2f z[32]) {
#pragma unroll
    for (int t = 0; t < 32; t++) {
        if ((t & ST) == 0) {
            const int u = t + ST;
            v2f x = z[t], y = z[u];
            v2f nx = pk_mul_s(ar, x);       // a*x
            nx = pk_fma_swl_s(ai, x, nx);
            nx = pk_fma_nn_s (br, y, nx);   // - conj(b)*y
            nx = pk_fma_swl_s(bi, y, nx);
            v2f ny = pk_mul_s(br, x);       // b*x
            ny = pk_fma_swl_s(bi, x, ny);
            ny = pk_fma_s    (ar, y, ny);   // + conj(a)*y
            ny = pk_fma_swh_s(ai, y, ny);
            z[t] = nx; z[u] = ny;
        }
    }
}

// ---------------- X correlators: <X_w> = sum_k Re(conj(z_k) z_{k^w}) --------
// cross wire (partner in lane^M): per-lane partial sum over the 32 own amps
template<int M>
__device__ __forceinline__ v2f xcorr_cross(const v2f z[32]) {
    v2f acc = (v2f){0.0f, 0.0f};
#pragma unroll
    for (int c = 0; c < 4; c++) {
        v2f p[8];
#pragma unroll
        for (int k = 0; k < 8; k++) {
            p[k].x = lxor<M>(z[c * 8 + k].x);
            p[k].y = lxor<M>(z[c * 8 + k].y);
        }
#pragma unroll
        for (int k = 0; k < 8; k++) acc = pk_fma(z[c * 8 + k], p[k], acc);
    }
    return acc;
}
// in-lane wire (reg bit ST): per-lane sum over the 16 pairs (each once)
template<int ST>
__device__ __forceinline__ v2f xcorr_inlane(const v2f z[32]) {
    v2f acc = (v2f){0.0f, 0.0f};
#pragma unroll
    for (int t = 0; t < 32; t++)
        if ((t & ST) == 0) acc = pk_fma(z[t], z[t + ST], acc);
    return acc;
}

// CZ t-part (5-bit): parity of adjacent-bit ANDs
__host__ __device__ constexpr bool czt5(int t) {
    return ((((t >> 4) & (t >> 3)) ^ ((t >> 3) & (t >> 2)) ^
             ((t >> 2) & (t >> 1)) ^ ((t >> 1) & t)) & 1) != 0;
}

__global__ __launch_bounds__(64, 2) void qdqn_kernel(
    const float* __restrict__ x,
    const float* __restrict__ ew1, const float* __restrict__ eb1,
    const float* __restrict__ ew2, const float* __restrict__ eb2,
    const float* __restrict__ qw,
    const float* __restrict__ dw1, const float* __restrict__ db1,
    const float* __restrict__ dw2, const float* __restrict__ db2,
    float* __restrict__ out, int B, int NL) {
    // one wave per block: all LDS exchange is wave-internal (in-order LDS),
    // ordered with wave_barrier only — no __syncthreads in the kernel.
    __shared__ __align__(16) float c_lds[32 * 4];
    __shared__ __align__(16) float hx[8][8];     // h / h2 exchange
    __shared__ __align__(16) float csx[8][16];   // (c,s) exchange

    const int tid = threadIdx.x;
    const int lane = tid;   // blockDim.x == 64
    // sample lane bits {0,1,3}; sample id bits {2,4,5} -> all-DPP cross wires
    const int g = (lane & 3) | ((lane >> 1) & 4);          // amp bits 7..5
    const int grp = ((lane >> 2) & 1) | ((lane >> 3) & 6); // sample in wave
    int s = blockIdx.x * 8 + grp;
    if (s >= B) s = B - 1;

    // ---- prefetch x early (overlaps coef computation) ----
    float xv[16];
    {
        const float4* xp = (const float4*)(x + s * 16);
#pragma unroll
        for (int i = 0; i < 4; i++) {
            float4 v = xp[i];
            xv[4*i] = v.x; xv[4*i+1] = v.y; xv[4*i+2] = v.z; xv[4*i+3] = v.w;
        }
    }

    // ---- Rot SU(2) coeffs once per wave: a = e^{-iA}c, b = e^{-iB}s ----
    const int n_gates = NL * 8;   // 32 <= 64: all in this wave
    if (tid < n_gates) {
        const int gg = tid;
        float phi = qw[3 * gg + 0], th = qw[3 * gg + 1], om = qw[3 * gg + 2];
        float c = __cosf(0.5f * th), sv = __sinf(0.5f * th);
        float A = 0.5f * (phi + om), Bb = 0.5f * (phi - om);
        float* o = c_lds + 4 * gg;
        o[0] =  __cosf(A) * c;   o[1] = -__sinf(A) * c;
        o[2] =  __cosf(Bb) * sv; o[3] = -__sinf(Bb) * sv;
    }
    __builtin_amdgcn_wave_barrier();

    // ---------------- encoder MLP, split across the 8 lanes ----------------
    float cq[8], sq[8];
    {
        // lane computes row g of W1
        float a = eb1[g];
#pragma unroll
        for (int i = 0; i < 16; i++) a = fmaf(ew1[g * 16 + i], xv[i], a);
        hx[grp][g] = fmaxf(a, 0.0f);
        __builtin_amdgcn_wave_barrier();
        float4 h01 = *(const float4*)&hx[grp][0];
        float4 h23 = *(const float4*)&hx[grp][4];
        // lane computes qubit g of layer 2 + transcendentals
        float b = eb2[g];
        b = fmaf(ew2[g*8+0], h01.x, b); b = fmaf(ew2[g*8+1], h01.y, b);
        b = fmaf(ew2[g*8+2], h01.z, b); b = fmaf(ew2[g*8+3], h01.w, b);
        b = fmaf(ew2[g*8+4], h23.x, b); b = fmaf(ew2[g*8+5], h23.y, b);
        b = fmaf(ew2[g*8+6], h23.z, b); b = fmaf(ew2[g*8+7], h23.w, b);
        float e = 1.0f - __fdividef(2.0f, __expf(2.0f * b) + 1.0f);  // tanh
        float ang = e * (0.5f * PI_F);
        float2* cso = (float2*)&csx[grp][2 * g];
        *cso = make_float2(__cosf(ang), __sinf(ang));
        __builtin_amdgcn_wave_barrier();
#pragma unroll
        for (int k = 0; k < 4; k++) {
            float4 v = *(const float4*)&csx[grp][4 * k];
            cq[2*k] = v.x; sq[2*k] = v.y; cq[2*k+1] = v.z; sq[2*k+1] = v.w;
        }
    }

    // ---- per-lane sign masks for cross wires q=0..2 (logical bit 2-q of g)
    int hiM[3], loM[3];
#pragma unroll
    for (int q = 0; q < 3; q++) {
        int hi = (g >> (2 - q)) & 1;
        hiM[q] = hi << 31;                 // flips ai when hi lane
        loM[q] = hiM[q] ^ 0x80000000;      // flips br when lo lane
    }

    // ---- CZ lane scalars: amp=(G<<5)|t; pairs (G2&G1)+(G1&G0)+(G0&t4)+t-part
    const int g0b = g & 1, g1b = (g >> 1) & 1, g2b = (g >> 2) & 1;
    const float mLo = ((g2b & g1b) ^ (g1b & g0b)) ? -1.0f : 1.0f;  // t < 16
    const float mHi = g0b ? -mLo : mLo;                            // t >= 16

    // ---------------- layer 0: product state, CZ folded --------------------
    v2f z[32];
    {
        // preload the 8 gate coeff float4s for layer 0
        float4 cA[8];
#pragma unroll
        for (int q = 0; q < 8; q++) cA[q] = *(const float4*)(c_lds + 4 * q);

        C2 P; P.re = 1.0f; P.im = 0.0f;
        C2 A[5], Bc[5];
#pragma unroll
        for (int q = 0; q < 8; q++) {
            float ar, ai, br, bi;
            make_G2(cA[q], cq[q], sq[q], ar, ai, br, bi);
            if (q < 3) {
                const bool hi = (g >> (2 - q)) & 1;
                C2 f; f.re = hi ? br : ar; f.im = hi ? bi : ai;  // column 0
                P = cmul(P, f);
            } else {
                A[q-3].re = ar;  A[q-3].im = ai;
                Bc[q-3].re = br; Bc[q-3].im = bi;
            }
        }
        z[0] = (v2f){P.re, P.im};
#pragma unroll
        for (int w = 0; w < 5; w++) {
            const int n = 1 << w;
#pragma unroll
            for (int i = n - 1; i >= 0; i--) {
                v2f v = z[i];
                z[2*i+1] = cmulv(v, Bc[w]);
                z[2*i]   = cmulv(v, A[w]);
            }
        }
#pragma unroll
        for (int t = 0; t < 32; t++) {
            const float m = (t < 16) ? mLo : mHi;
            z[t] = czt5(t) ? pk_mul_neg_s(m, z[t]) : pk_mul_s(m, z[t]);
        }
    }

    // ---------------- layers 1..NL-1 ---------------------------------------
    for (int l = 1; l < NL; l++) {
        const int gb = l * 8;
        // hoist the whole layer's coeffs into registers — ds latency issued
        // once per layer instead of interleaved per-gate
        float4 cA[8];
#pragma unroll
        for (int q = 0; q < 8; q++) cA[q] = *(const float4*)(c_lds + 4 * (gb + q));

        float ar, ai, br, bi;
        make_G2(cA[0], cq[0], sq[0], ar, ai, br, bi);
        su2_cross<8>(ar, fxor(ai,hiM[0]), fxor(br,loM[0]), bi, z);
        make_G2(cA[1], cq[1], sq[1], ar, ai, br, bi);
        su2_cross<2>(ar, fxor(ai,hiM[1]), fxor(br,loM[1]), bi, z);
        make_G2(cA[2], cq[2], sq[2], ar, ai, br, bi);
        su2_cross<1>(ar, fxor(ai,hiM[2]), fxor(br,loM[2]), bi, z);
        make_G2(cA[3], cq[3], sq[3], ar, ai, br, bi);
        su2_inlane<16>(ar, ai, br, bi, z);
        make_G2(cA[4], cq[4], sq[4], ar, ai, br, bi);
        su2_inlane<8>(ar, ai, br, bi, z);
        make_G2(cA[5], cq[5], sq[5], ar, ai, br, bi);
        su2_inlane<4>(ar, ai, br, bi, z);
        make_G2(cA[6], cq[6], sq[6], ar, ai, br, bi);
        su2_inlane<2>(ar, ai, br, bi, z);
        make_G2(cA[7], cq[7], sq[7], ar, ai, br, bi);
        su2_inlane<1>(ar, ai, br, bi, z);
        // CZ diagonal
#pragma unroll
        for (int t = 0; t < 32; t++) {
            const float m = (t < 16) ? mLo : mHi;
            z[t] = czt5(t) ? pk_mul_neg_s(m, z[t]) : pk_mul_s(m, z[t]);
        }
    }

    // ---------------- readout: rotated observables --------------------------
    // The final RY(T_w) layer is NOT applied to the state. Instead:
    //   <Z_w>_final = cosT_w * <Z_w> - sinT_w * <X_w>   (RY^dag Z RY identity;
    // RY's on other wires commute through Z_w). cq/sq hold half-angle cos/sin:
    // cosT = cq^2 - sq^2, sinT = 2*cq*sq. In-lane correlators count each pair
    // once per lane (-> coeff 2*sinT); cross correlators count each ordered
    // pair once across the two lanes (-> coeff sinT after the all-reduce).
    v2f xa[8];
    xa[0] = xcorr_cross<8>(z);
    xa[1] = xcorr_cross<2>(z);
    xa[2] = xcorr_cross<1>(z);
    xa[3] = xcorr_inlane<16>(z);
    xa[4] = xcorr_inlane<8>(z);
    xa[5] = xcorr_inlane<4>(z);
    xa[6] = xcorr_inlane<2>(z);
    xa[7] = xcorr_inlane<1>(z);

    float p[32];
#pragma unroll
    for (int t = 0; t < 32; t++) p[t] = fmaf(z[t].x, z[t].x, z[t].y * z[t].y);

    float s16[16], zW[8];
    {
        float d = 0.0f;
#pragma unroll
        for (int i = 0; i < 16; i++) {
            s16[i] = p[2*i] + p[2*i+1];
            d += p[2*i] - p[2*i+1];
        }
        zW[7] = d;
        float s8[8]; d = 0.0f;
#pragma unroll
        for (int i = 0; i < 8; i++) {
            s8[i] = s16[2*i] + s16[2*i+1];
            d += s16[2*i] - s16[2*i+1];
        }
        zW[6] = d;
        float s4[4]; d = 0.0f;
#pragma unroll
        for (int i = 0; i < 4; i++) {
            s4[i] = s8[2*i] + s8[2*i+1];
            d += s8[2*i] - s8[2*i+1];
        }
        zW[5] = d;
        float s2a = s4[0] + s4[1], s2b = s4[2] + s4[3];
        zW[4] = (s4[0] - s4[1]) + (s4[2] - s4[3]);
        float sumP = s2a + s2b;
        zW[3] = s2a - s2b;
        zW[0] = g2b ? -sumP : sumP;
        zW[1] = g1b ? -sumP : sumP;
        zW[2] = g0b ? -sumP : sumP;
    }

    // rotate observables (per-lane partials; linear in the later all-reduce)
#pragma unroll
    for (int w = 0; w < 8; w++) {
        const float c2 = fmaf(cq[w], cq[w], -sq[w] * sq[w]);   // cos T
        const float cs = cq[w] * sq[w];
        const float s2 = (w < 3 ? 2.0f : 4.0f) * cs;           // sinT (x2 in-lane)
        zW[w] = fmaf(c2, zW[w], -s2 * (xa[w].x + xa[w].y));
    }

    // all-reduce across the 8 lanes of the sample (bits 0,1,3 -> all DPP)
#pragma unroll
    for (int w = 0; w < 8; w++) zW[w] += lxor<1>(zW[w]);
#pragma unroll
    for (int w = 0; w < 8; w++) zW[w] += lxor<2>(zW[w]);
#pragma unroll
    for (int w = 0; w < 8; w++) zW[w] += lxor<8>(zW[w]);

    // ---------------- decoder MLP, split across lanes ----------------------
    {
        float a = db1[g];
#pragma unroll
        for (int w = 0; w < 8; w++) a = fmaf(dw1[g * 8 + w], zW[w], a);
        hx[grp][g] = fmaxf(a, 0.0f);
        __builtin_amdgcn_wave_barrier();
        float4 h01 = *(const float4*)&hx[grp][0];
        float4 h23 = *(const float4*)&hx[grp][4];
        const int o = g & 3;   // lanes g and g+4 compute identical output o
        float acc = db2[o];
        acc = fmaf(dw2[o*8+0], h01.x, acc); acc = fmaf(dw2[o*8+1], h01.y, acc);
        acc = fmaf(dw2[o*8+2], h01.z, acc); acc = fmaf(dw2[o*8+3], h01.w, acc);
        acc = fmaf(dw2[o*8+4], h23.x, acc); acc = fmaf(dw2[o*8+5], h23.y, acc);
        acc = fmaf(dw2[o*8+6], h23.z, acc); acc = fmaf(dw2[o*8+7], h23.w, acc);
        out[s * 4 + o] = acc;
    }
}

extern "C" void kernel_launch(void* const* d_in, const int* in_sizes, int n_in,
                              void* d_out, int out_size, void* d_ws, size_t ws_size,
                              hipStream_t stream) {
    const float* x   = (const float*)d_in[0];
    const float* ew1 = (const float*)d_in[1];
    const float* eb1 = (const float*)d_in[2];
    const float* ew2 = (const float*)d_in[3];
    const float* eb2 = (const float*)d_in[4];
    const float* qw  = (const float*)d_in[5];
    const float* dw1 = (const float*)d_in[6];
    const float* db1 = (const float*)d_in[7];
    const float* dw2 = (const float*)d_in[8];
    const float* db2 = (const float*)d_in[9];
    float* out = (float*)d_out;

    int B = in_sizes[0] / 16;        // 32768
    int n_gates = in_sizes[5] / 3;   // 32
    int NL = n_gates / 8;            // 4

    // 8 samples per 64-thread block (1 wave x 8 samples/wave)
    int blocks = (B + 7) / 8;
    qdqn_kernel<<<blocks, 64, 0, stream>>>(x, ew1, eb1, ew2, eb2, qw,
                                           dw1, db1, dw2, db2, out, B, NL);
}